// Round 18
// baseline (104.101 us; speedup 1.0000x reference)
//
#include <hip/hip_runtime.h>
#include <stdint.h>

#define NT 2048     // tokens
#define TD 1024     // token dim
#define NH 16       // heads
static constexpr float SCL = 0.18033688011112042f;  // beta*log2(e), applied in exp2

typedef __attribute__((ext_vector_type(8))) short bf16x8;
typedef __attribute__((ext_vector_type(4))) float f32x4;
typedef __attribute__((ext_vector_type(16))) float f32x16;

__device__ __forceinline__ float bf2f(unsigned short u){
  union { uint32_t u32; float f; } v; v.u32 = ((uint32_t)u) << 16; return v.f;
}
__device__ __forceinline__ unsigned short f2bf(float f){
  union { float f; uint32_t u; } v; v.f = f;
  uint32_t r = v.u + 0x7fffu + ((v.u >> 16) & 1u);   // RNE
  return (unsigned short)(r >> 16);
}

// ------------------------------------------------------------------
// prep (round-16/17 verified): packs g -> PG (A-frags), [Wk;Wq] -> PW
// (B-frags), twqk -> TWP (out-GEMM B-frags).
// ------------------------------------------------------------------
__global__ __launch_bounds__(256) void prep_kernel(
    const float* __restrict__ g, const float* __restrict__ Wk, const float* __restrict__ Wq,
    unsigned short* __restrict__ PG, unsigned short* __restrict__ PW,
    unsigned short* __restrict__ TWP)
{
  int b = blockIdx.x;
  int tid = threadIdx.x;
  if (b < 2048) {
    bool isW = (b >= 1024);
    int bb = isW ? b - 1024 : b;
    int dg = bb & 15, rb2 = bb >> 4;
    __shared__ float tile[32][65];
    const float* src;
    int rbase;
    if (!isW) { src = g; rbase = rb2 * 32; }
    else if (rb2 < 32) { src = Wk; rbase = rb2 * 32; }
    else { src = Wq; rbase = rb2 * 32 - 1024; }
    int r = tid >> 3, c0 = (tid & 7) * 8;
    const float* s = src + (size_t)(rbase + r) * 1024 + dg * 64 + c0;
    *(f32x4*)&tile[r][c0]     = *(const f32x4*)s;
    *(f32x4*)&tile[r][c0 + 4] = *(const f32x4*)(s + 4);
    __syncthreads();
    int dzl = tid >> 6, l = tid & 63;
    int dz = dg * 4 + dzl;
    unsigned short ob[8];
    #pragma unroll
    for (int e = 0; e < 8; e++)
      ob[e] = f2bf(tile[l & 31][dzl * 16 + 8 * (l >> 5) + e]);
    unsigned short* dst = (isW ? PW : PG) + ((size_t)(rb2 * 64 + dz) * 64 + l) * 8;
    *(ushort4*)dst       = *(ushort4*)&ob[0];
    *(ushort4*)(dst + 4) = *(ushort4*)&ob[4];
  } else {
    int t = b - 2048;                  // 512 = 32 db x 16 jzg
    int db = t & 31, jzg = t >> 5;
    int d0 = db * 32, j0 = jzg * 128;
    __shared__ unsigned short tile[128][33];
    const float* src = (j0 < 1024) ? Wq : Wk;
    int jb = (j0 < 1024) ? j0 : (j0 - 1024);
    #pragma unroll
    for (int i = 0; i < 16; i++) {
      int idx = i * 256 + tid, r = idx >> 5, c = idx & 31;
      tile[r][c] = f2bf(src[(size_t)(jb + r) * 1024 + d0 + c]);
    }
    __syncthreads();
    int jq = tid >> 6, l = tid & 63;
    #pragma unroll
    for (int f = 0; f < 2; f++) {
      int jzl = jq * 2 + f;
      unsigned short ob[8];
      #pragma unroll
      for (int e = 0; e < 8; e++)
        ob[e] = tile[jzl * 16 + 8 * (l >> 5) + e][l & 31];
      unsigned short* dst = TWP + ((size_t)(db * 128 + jzg * 8 + jzl) * 64 + l) * 8;
      *(ushort4*)dst       = *(ushort4*)&ob[0];
      *(ushort4*)(dst + 4) = *(ushort4*)&ob[4];
    }
  }
}

// ------------------------------------------------------------------
// kq_kernel (round-16/17 verified): zero-barrier packed GEMM; epilogue
// writes PCK frags + (cblk<16) PBT frags. Occupancy 3 blocks/CU.
// ------------------------------------------------------------------
__global__ __launch_bounds__(256, 3) void kq_kernel(
    const unsigned short* __restrict__ PG,
    const unsigned short* __restrict__ PW,
    unsigned short* __restrict__ PCK,
    unsigned short* __restrict__ PBT)
{
  __shared__ __align__(16) float Red[2][64][68];
  int tid = threadIdx.x, l = tid & 63, w = tid >> 6;
  int zr = l & 31, hi = l >> 5;
  int lin = blockIdx.x;
  int wgid = (lin & 7) * 128 + (lin >> 3);
  int tokb = wgid >> 5, cblk = wgid & 31;
  const bf16x8* PGf = (const bf16x8*)PG;
  const bf16x8* PWf = (const bf16x8*)PW;

  f32x16 acc[2][2] = {};                      // [th tok-half][ch c-half]
  bf16x8 a_c[2], b_c[2];
  auto loadx = [&](bf16x8 (&a_)[2], bf16x8 (&b_)[2], int dz){
    #pragma unroll
    for (int th = 0; th < 2; th++)
      a_[th] = PGf[((size_t)(tokb * 2 + th) * 64 + dz) * 64 + l];
    #pragma unroll
    for (int ch = 0; ch < 2; ch++)
      b_[ch] = PWf[((size_t)(cblk * 2 + ch) * 64 + dz) * 64 + l];
  };
  loadx(a_c, b_c, w * 16);
  for (int it = 0; it < 16; it++) {
    bf16x8 a_n[2], b_n[2];
    if (it + 1 < 16) loadx(a_n, b_n, w * 16 + it + 1);
    #pragma unroll
    for (int th = 0; th < 2; th++)
      #pragma unroll
      for (int ch = 0; ch < 2; ch++)
        acc[th][ch] = __builtin_amdgcn_mfma_f32_32x32x16_bf16(a_c[th], b_c[ch], acc[th][ch], 0, 0, 0);
    #pragma unroll
    for (int i = 0; i < 2; i++) { a_c[i] = a_n[i]; b_c[i] = b_n[i]; }
  }
  if (w >= 2) {
    #pragma unroll
    for (int th = 0; th < 2; th++)
      #pragma unroll
      for (int ch = 0; ch < 2; ch++) {
        int c = ch * 32 + zr;
        #pragma unroll
        for (int u = 0; u < 4; u++) {
          int tk = th * 32 + 8 * u + 4 * hi;
          f32x4 q;
          q[0] = acc[th][ch][4 * u];     q[1] = acc[th][ch][4 * u + 1];
          q[2] = acc[th][ch][4 * u + 2]; q[3] = acc[th][ch][4 * u + 3];
          *(f32x4*)&Red[w - 2][c][tk] = q;
        }
      }
  }
  __syncthreads();
  if (w < 2) {
    #pragma unroll
    for (int th = 0; th < 2; th++)
      #pragma unroll
      for (int ch = 0; ch < 2; ch++) {
        int c = ch * 32 + zr;
        #pragma unroll
        for (int u = 0; u < 4; u++) {
          int tk = th * 32 + 8 * u + 4 * hi;
          float* slot = &Red[w][c][tk];
          f32x4 q = *(f32x4*)slot;
          q[0] += acc[th][ch][4 * u];     q[1] += acc[th][ch][4 * u + 1];
          q[2] += acc[th][ch][4 * u + 2]; q[3] += acc[th][ch][4 * u + 3];
          *(f32x4*)slot = q;
        }
      }
  }
  __syncthreads();
  int p = tid >> 2, c16 = (tid & 3) * 16;
  int tok = tokb * 64 + p;
  unsigned short ob[16];
  #pragma unroll
  for (int i = 0; i < 16; i++)
    ob[i] = f2bf(Red[0][c16 + i][p] + Red[1][c16 + i][p]);
  int rb = tok >> 5, tl = tok & 31, kz = tid & 3;
  unsigned short* dstp = PCK + (((size_t)(cblk * 64 + rb) * 4 + kz) * 64) * 8;
  *(ushort4*)(dstp + tl * 8)            = *(ushort4*)&ob[0];
  *(ushort4*)(dstp + tl * 8 + 4)        = *(ushort4*)&ob[4];
  *(ushort4*)(dstp + (32 + tl) * 8)     = *(ushort4*)&ob[8];
  *(ushort4*)(dstp + (32 + tl) * 8 + 4) = *(ushort4*)&ob[12];
  if (cblk < 16) {
    int h = cblk;
    int zb = (tid >> 7) & 1, qh = (tid >> 6) & 1;
    int cl = zb * 32 + zr;
    #pragma unroll
    for (int ks = 0; ks < 2; ks++) {
      unsigned short o2[8];
      #pragma unroll
      for (int e = 0; e < 8; e++) {
        int ql = 32 * qh + 16 * ks + 8 * (e >> 2) + 4 * hi + (e & 3);
        o2[e] = f2bf(Red[0][cl][ql] + Red[1][cl][ql]);
      }
      unsigned short* dq = PBT +
          ((((size_t)(h * 2 + zb) * 64 + tokb * 2 + qh) * 2 + ks) * 64 + l) * 8;
      *(ushort4*)dq       = *(ushort4*)&o2[0];
      *(ushort4*)(dq + 4) = *(ushort4*)&o2[4];
    }
  }
}

// ------------------------------------------------------------------
// fused (verified core): zero-barrier packed-load kernel. F1 emits QSTP
// fragments via Qt LDS tile (template-sized away for F2). WPE = blocks/CU.
// ------------------------------------------------------------------
template<bool DIV, int WPE>
__global__ __launch_bounds__(256, WPE) void fused_kernel(
    const unsigned short* __restrict__ PCK,   // packed CKQ fragments
    const unsigned short* __restrict__ PBX,   // PBT (F1) or QSTP (F2)
    unsigned short* __restrict__ PA,          // packed out-GEMM A operand
    unsigned short* __restrict__ QSTP)        // F1 only: packed Q^T/L frags
{
  __shared__ __align__(16) float Red[2][64][68];   // ~34.8 KB
  __shared__ float L_lds[64];
  __shared__ unsigned short Qt[DIV ? 64 * 68 : 8]; // 8.7 KB (F1) / 16 B (F2)
  int tid = threadIdx.x, l = tid & 63, w = tid >> 6;
  int zr = l & 31, hi = l >> 5;
  int lin = blockIdx.x;                      // 512 blocks, bijective XCD swizzle
  int wgid = (lin & 7) * 64 + (lin >> 3);
  int h = wgid >> 5, pB = wgid & 31, p0 = pB * 64;
  int cbA = DIV ? h : 16 + h;                // inner cols (F1: K, F2: Q)
  int cbB = DIV ? 16 + h : h;                // persist cols (F1: Q, F2: K)
  const bf16x8* PCKf = (const bf16x8*)PCK;
  const bf16x8* PBXf = (const bf16x8*)PBX;

  // persistent S B-fragments (2 x 32-persist sets)
  bf16x8 bs[2][4];
  #pragma unroll
  for (int ps = 0; ps < 2; ps++)
    #pragma unroll
    for (int kz = 0; kz < 4; kz++)
      bs[ps][kz] = PCKf[((size_t)(cbB * 64 + pB * 2 + ps) * 4 + kz) * 64 + l];

  auto load = [&](bf16x8 (&a_)[4], bf16x8 (&pb_)[2][2], int rb){
    #pragma unroll
    for (int kz = 0; kz < 4; kz++)
      a_[kz] = PCKf[((size_t)(cbA * 64 + rb) * 4 + kz) * 64 + l];
    #pragma unroll
    for (int zb = 0; zb < 2; zb++)
      #pragma unroll
      for (int ks = 0; ks < 2; ks++)
        pb_[zb][ks] = PBXf[((size_t)((h * 2 + zb) * 64 + rb) * 2 + ks) * 64 + l];
  };

  f32x16 acc_pv[2][2] = {};                  // [ps][zb]
  float lsum[2] = {0.f, 0.f};
  bf16x8 a_c[4], pb_c[2][2];
  load(a_c, pb_c, w * 16);

  for (int t = 0; t < 16; t++) {
    bf16x8 a_n[4], pb_n[2][2];
    if (t + 1 < 16) load(a_n, pb_n, w * 16 + t + 1);
    f32x16 acc_s[2] = {};
    #pragma unroll
    for (int kz = 0; kz < 4; kz++) {
      acc_s[0] = __builtin_amdgcn_mfma_f32_32x32x16_bf16(a_c[kz], bs[0][kz], acc_s[0], 0, 0, 0);
      acc_s[1] = __builtin_amdgcn_mfma_f32_32x32x16_bf16(a_c[kz], bs[1][kz], acc_s[1], 0, 0, 0);
    }
    union { bf16x8 v; uint32_t u[4]; } pu[2][2];
    #pragma unroll
    for (int ps = 0; ps < 2; ps++) {
      float ev[16];
      #pragma unroll
      for (int r = 0; r < 16; r++) ev[r] = exp2f(acc_s[ps][r] * SCL);
      if (DIV) {
        #pragma unroll
        for (int r = 0; r < 16; r++) lsum[ps] += ev[r];
      }
      #pragma unroll
      for (int ks = 0; ks < 2; ks++)
        #pragma unroll
        for (int i = 0; i < 4; i++)
          asm("v_cvt_pk_bf16_f32 %0, %1, %2"
              : "=v"(pu[ps][ks].u[i]) : "v"(ev[8 * ks + 2 * i]), "v"(ev[8 * ks + 2 * i + 1]));
    }
    #pragma unroll
    for (int zb = 0; zb < 2; zb++)
      #pragma unroll
      for (int ks = 0; ks < 2; ks++) {
        acc_pv[0][zb] = __builtin_amdgcn_mfma_f32_32x32x16_bf16(pu[0][ks].v, pb_c[zb][ks], acc_pv[0][zb], 0, 0, 0);
        acc_pv[1][zb] = __builtin_amdgcn_mfma_f32_32x32x16_bf16(pu[1][ks].v, pb_c[zb][ks], acc_pv[1][zb], 0, 0, 0);
      }
    #pragma unroll
    for (int kz = 0; kz < 4; kz++) a_c[kz] = a_n[kz];
    #pragma unroll
    for (int zb = 0; zb < 2; zb++)
      #pragma unroll
      for (int ks = 0; ks < 2; ks++) pb_c[zb][ks] = pb_n[zb][ks];
  }

  // ---- cross-wave (4 inner-quarter) two-phase reduction
  if (w >= 2) {
    #pragma unroll
    for (int ps = 0; ps < 2; ps++)
      #pragma unroll
      for (int zb = 0; zb < 2; zb++) {
        int z = zb * 32 + zr;
        #pragma unroll
        for (int u = 0; u < 4; u++) {
          int p = ps * 32 + 8 * u + 4 * hi;
          f32x4 q;
          q[0] = acc_pv[ps][zb][4 * u];     q[1] = acc_pv[ps][zb][4 * u + 1];
          q[2] = acc_pv[ps][zb][4 * u + 2]; q[3] = acc_pv[ps][zb][4 * u + 3];
          *(f32x4*)&Red[w - 2][z][p] = q;
        }
      }
  }
  if (DIV && tid < 64) L_lds[tid] = 0.f;
  __syncthreads();
  if (w < 2) {
    #pragma unroll
    for (int ps = 0; ps < 2; ps++)
      #pragma unroll
      for (int zb = 0; zb < 2; zb++) {
        int z = zb * 32 + zr;
        #pragma unroll
        for (int u = 0; u < 4; u++) {
          int p = ps * 32 + 8 * u + 4 * hi;
          float* slot = &Red[w][z][p];
          f32x4 q = *(f32x4*)slot;
          q[0] += acc_pv[ps][zb][4 * u];     q[1] += acc_pv[ps][zb][4 * u + 1];
          q[2] += acc_pv[ps][zb][4 * u + 2]; q[3] += acc_pv[ps][zb][4 * u + 3];
          *(f32x4*)slot = q;
        }
      }
  }
  if (DIV) {
    #pragma unroll
    for (int ps = 0; ps < 2; ps++) {
      float s = lsum[ps];
      s += __shfl_xor(s, 32);
      if (hi == 0) atomicAdd(&L_lds[ps * 32 + zr], s);
    }
  }
  __syncthreads();
  // ---- packed PA write: thread -> tok = p0 + (tid>>2), j-chunk (tid&3)*16
  int p = tid >> 2, z16 = (tid & 3) * 16;
  float inv = DIV ? 1.0f / L_lds[p] : 1.0f;
  int cbase = DIV ? h * 64 : TD + h * 64;
  int jz = (cbase + z16) >> 4;
  int tok = p0 + p, tb = tok >> 5, tl = tok & 31;
  unsigned short ob[16];
  #pragma unroll
  for (int i = 0; i < 16; i++) {
    int z = z16 + i;
    float x = Red[0][z][p] + Red[1][z][p];
    ob[i] = f2bf(x * inv);
  }
  unsigned short* dst = PA + (((size_t)jz * 64 + tb) * 64) * 8;
  *(ushort4*)(dst + tl * 8)            = *(ushort4*)&ob[0];
  *(ushort4*)(dst + tl * 8 + 4)        = *(ushort4*)&ob[4];
  *(ushort4*)(dst + (32 + tl) * 8)     = *(ushort4*)&ob[8];
  *(ushort4*)(dst + (32 + tl) * 8 + 4) = *(ushort4*)&ob[12];

  // ---- F1 only: emit QSTP fragments (pack_pbx<true> folded in)
  if (DIV) {
    #pragma unroll
    for (int ps = 0; ps < 2; ps++) {
      float iq = 1.0f / L_lds[ps * 32 + zr];
      #pragma unroll
      for (int kz = 0; kz < 4; kz++) {
        unsigned short t8[8];
        #pragma unroll
        for (int e = 0; e < 8; e++)
          t8[e] = f2bf(bf2f((unsigned short)bs[ps][kz][e]) * iq);
        unsigned short* qd = &Qt[(ps * 32 + zr) * 68 + kz * 16 + 8 * hi];
        *(ushort4*)qd       = *(ushort4*)&t8[0];
        *(ushort4*)(qd + 4) = *(ushort4*)&t8[4];
      }
    }
    __syncthreads();
    int zb = (tid >> 7) & 1, qh = (tid >> 6) & 1;
    #pragma unroll
    for (int ks = 0; ks < 2; ks++) {
      unsigned short o2[8];
      #pragma unroll
      for (int e = 0; e < 8; e++) {
        int ql = 32 * qh + 16 * ks + 8 * (e >> 2) + 4 * hi + (e & 3);
        o2[e] = Qt[ql * 68 + zb * 32 + zr];
      }
      unsigned short* dq = QSTP +
          ((((size_t)(h * 2 + zb) * 64 + pB * 2 + qh) * 2 + ks) * 64 + l) * 8;
      *(ushort4*)dq       = *(ushort4*)&o2[0];
      *(ushort4*)(dq + 4) = *(ushort4*)&o2[4];
    }
  }
}

// ------------------------------------------------------------------
// out_kernel (verified): out = -(PA . TWP^T). Occupancy 3 blocks/CU.
// ------------------------------------------------------------------
__global__ __launch_bounds__(256, 3) void out_kernel(
    const unsigned short* __restrict__ PA,
    const unsigned short* __restrict__ TWP,
    float* __restrict__ out)
{
  __shared__ __align__(16) float Red[2][64][68];
  int tid = threadIdx.x, l = tid & 63, w = tid >> 6;
  int zr = l & 31, hi = l >> 5;
  int lin = blockIdx.x;
  int wgid = (lin & 7) * 64 + (lin >> 3);
  int tokb = wgid >> 4, db2 = wgid & 15;
  const bf16x8* PAf = (const bf16x8*)PA;
  const bf16x8* TWf = (const bf16x8*)TWP;

  f32x16 acc[2][2] = {};                      // [th tok-half][dh d-half]
  bf16x8 a_c[2], b_c[2];
  auto loadx = [&](bf16x8 (&a_)[2], bf16x8 (&b_)[2], int jz){
    #pragma unroll
    for (int th = 0; th < 2; th++)
      a_[th] = PAf[((size_t)jz * 64 + tokb * 2 + th) * 64 + l];
    #pragma unroll
    for (int dh = 0; dh < 2; dh++)
      b_[dh] = TWf[((size_t)(db2 * 2 + dh) * 128 + jz) * 64 + l];
  };
  loadx(a_c, b_c, w * 32);
  for (int it = 0; it < 32; it++) {
    bf16x8 a_n[2], b_n[2];
    if (it + 1 < 32) loadx(a_n, b_n, w * 32 + it + 1);
    #pragma unroll
    for (int th = 0; th < 2; th++)
      #pragma unroll
      for (int dh = 0; dh < 2; dh++)
        acc[th][dh] = __builtin_amdgcn_mfma_f32_32x32x16_bf16(a_c[th], b_c[dh], acc[th][dh], 0, 0, 0);
    #pragma unroll
    for (int i = 0; i < 2; i++) { a_c[i] = a_n[i]; b_c[i] = b_n[i]; }
  }
  if (w >= 2) {
    #pragma unroll
    for (int th = 0; th < 2; th++)
      #pragma unroll
      for (int dh = 0; dh < 2; dh++) {
        int d = dh * 32 + zr;
        #pragma unroll
        for (int u = 0; u < 4; u++) {
          int tk = th * 32 + 8 * u + 4 * hi;
          f32x4 q;
          q[0] = acc[th][dh][4 * u];     q[1] = acc[th][dh][4 * u + 1];
          q[2] = acc[th][dh][4 * u + 2]; q[3] = acc[th][dh][4 * u + 3];
          *(f32x4*)&Red[w - 2][d][tk] = q;
        }
      }
  }
  __syncthreads();
  if (w < 2) {
    #pragma unroll
    for (int th = 0; th < 2; th++)
      #pragma unroll
      for (int dh = 0; dh < 2; dh++) {
        int d = dh * 32 + zr;
        #pragma unroll
        for (int u = 0; u < 4; u++) {
          int tk = th * 32 + 8 * u + 4 * hi;
          float* slot = &Red[w][d][tk];
          f32x4 q = *(f32x4*)slot;
          q[0] += acc[th][dh][4 * u];     q[1] += acc[th][dh][4 * u + 1];
          q[2] += acc[th][dh][4 * u + 2]; q[3] += acc[th][dh][4 * u + 3];
          *(f32x4*)slot = q;
        }
      }
  }
  __syncthreads();
  int p = tid >> 2, d16 = (tid & 3) * 16;
  float* dst = out + (size_t)(tokb * 64 + p) * 1024 + db2 * 64 + d16;
  #pragma unroll
  for (int i4 = 0; i4 < 16; i4 += 4) {
    f32x4 r;
    #pragma unroll
    for (int j = 0; j < 4; j++)
      r[j] = -(Red[0][d16 + i4 + j][p] + Red[1][d16 + i4 + j][p]);
    *(f32x4*)(dst + i4) = r;
  }
}

// ------------------------------------------------------------------
extern "C" void kernel_launch(void* const* d_in, const int* in_sizes, int n_in,
                              void* d_out, int out_size, void* d_ws, size_t ws_size,
                              hipStream_t stream)
{
  (void)in_sizes; (void)n_in; (void)out_size; (void)ws_size;
  const float* g  = (const float*)d_in[0];
  const float* Wk = (const float*)d_in[1];
  const float* Wq = (const float*)d_in[2];

  char* ws = (char*)d_ws;
  size_t off = 0;
  auto alloc = [&](size_t b) -> char* {
    char* p = ws + off; off += (b + 255) & ~((size_t)255); return p;
  };
  unsigned short* PG   = (unsigned short*)alloc((size_t)NT * TD * 2);     // 4 MB
  unsigned short* PW   = (unsigned short*)alloc((size_t)2048 * TD * 2);   // 4 MB
  unsigned short* TWP  = (unsigned short*)alloc((size_t)TD * 2048 * 2);   // 4 MB
  unsigned short* PCK  = (unsigned short*)alloc((size_t)NT * 2048 * 2);   // 8 MB
  unsigned short* PBT  = (unsigned short*)alloc((size_t)TD * NT * 2);     // 4 MB
  unsigned short* QSTP = (unsigned short*)alloc((size_t)TD * NT * 2);     // 4 MB
  unsigned short* PA   = (unsigned short*)alloc((size_t)NT * 2048 * 2);   // 8 MB

  // pack g -> PG, [Wk;Wq] -> PW, twqk -> TWP
  prep_kernel<<<dim3(2560), dim3(256), 0, stream>>>(g, Wk, Wq, PG, PW, TWP);

  // KQ GEMM -> PCK fragments + PBT fragments (pack folded into epilogue)
  kq_kernel<<<dim3(1024), dim3(256), 0, stream>>>(PG, PW, PCK, PBT);

  // F1: B1 -> PA fragments jz 0..63; QSTP fragments (pack folded in)
  fused_kernel<true, 2><<<dim3(512), dim3(256), 0, stream>>>(PCK, PBT, PA, QSTP);

  // F2: B2 -> PA fragments jz 64..127
  fused_kernel<false, 3><<<dim3(512), dim3(256), 0, stream>>>(PCK, QSTP, PA, nullptr);

  // out = -(PA . TWP^T) from packed fragments
  out_kernel<<<dim3(512), dim3(256), 0, stream>>>(PA, TWP, (float*)d_out);
}